// Round 1
// baseline (1196.106 us; speedup 1.0000x reference)
//
#include <hip/hip_runtime.h>

#define NN 50000
#define EE 800000
#define FIN 128
#define HH 256
#define NL 3

// ---------------- utility kernels ----------------
__global__ void k_zero_i32(int* __restrict__ p, int n){
    int i = blockIdx.x*256 + threadIdx.x;
    if (i < n) p[i] = 0;
}

__global__ void k_count_deg(const int* __restrict__ dst, int* __restrict__ deg){
    int i = blockIdx.x*256 + threadIdx.x;
    if (i < EE) atomicAdd(&deg[dst[i]], 1);
}

__global__ void k_block_sum(const int* __restrict__ deg, int* __restrict__ bsum){
    __shared__ int s[1024];
    int i = blockIdx.x*1024 + threadIdx.x;
    s[threadIdx.x] = (i < NN) ? deg[i] : 0;
    __syncthreads();
    for (int o = 512; o > 0; o >>= 1){
        if (threadIdx.x < o) s[threadIdx.x] += s[threadIdx.x + o];
        __syncthreads();
    }
    if (threadIdx.x == 0) bsum[blockIdx.x] = s[0];
}

__global__ void k_scan_bsum(int* __restrict__ bsum, int nb){
    if (threadIdx.x == 0 && blockIdx.x == 0){
        int run = 0;
        for (int i = 0; i < nb; ++i){ int v = bsum[i]; bsum[i] = run; run += v; }
    }
}

__global__ void k_make_off(const int* __restrict__ deg, const int* __restrict__ bsum,
                           int* __restrict__ off, int* __restrict__ pos,
                           float* __restrict__ invd){
    __shared__ int s[1024];
    int t = threadIdx.x;
    int i = blockIdx.x*1024 + t;
    int v = (i < NN) ? deg[i] : 0;
    s[t] = v; __syncthreads();
    for (int o = 1; o < 1024; o <<= 1){
        int add = (t >= o) ? s[t - o] : 0;
        __syncthreads();
        s[t] += add;
        __syncthreads();
    }
    if (i < NN){
        int excl = s[t] - v + bsum[blockIdx.x];
        off[i] = excl; pos[i] = excl;
        invd[i] = 1.0f / fmaxf((float)v, 1.0f);
    }
}

__global__ void k_build_csr(const int* __restrict__ src, const int* __restrict__ dst,
                            int* __restrict__ pos, int* __restrict__ csr){
    int i = blockIdx.x*256 + threadIdx.x;
    if (i < EE){
        int p = atomicAdd(&pos[dst[i]], 1);
        csr[p] = src[i];
    }
}

__global__ void k_transpose_proj(const float* __restrict__ Wp, float* __restrict__ Wpt){
    int i = blockIdx.x*256 + threadIdx.x; // i = k*HH + n
    if (i < FIN*HH){
        int k = i / HH, n = i % HH;
        Wpt[i] = Wp[n*FIN + k];
    }
}

__global__ void k_transpose_layers(const float* __restrict__ Wl, const float* __restrict__ Wr,
                                   float* __restrict__ Wt){
    int i = blockIdx.x*256 + threadIdx.x; // [l][k(0..511)][n]
    const int total = NL*2*HH*HH;
    if (i < total){
        int n = i % HH;
        int k = (i / HH) % (2*HH);
        int l = i / (HH*2*HH);
        float v = (k < HH) ? Wl[(size_t)l*HH*HH + (size_t)n*HH + k]
                           : Wr[(size_t)l*HH*HH + (size_t)n*HH + (k - HH)];
        Wt[i] = v;
    }
}

// ---------------- aggregation: one wave per node ----------------
__global__ __launch_bounds__(256) void k_aggregate(
    const float* __restrict__ hin, const int* __restrict__ csr,
    const int* __restrict__ off, const int* __restrict__ deg,
    const float* __restrict__ invd, float* __restrict__ agg)
{
    int wave = threadIdx.x >> 6, lane = threadIdx.x & 63;
    int node = blockIdx.x*4 + wave;
    if (node >= NN) return;
    int o = off[node], d = deg[node];
    float4 acc = make_float4(0.f, 0.f, 0.f, 0.f);
    int j = 0;
    for (; j + 2 <= d; j += 2){
        int s0 = csr[o + j], s1 = csr[o + j + 1];
        float4 v0 = *(const float4*)&hin[(size_t)s0*HH + lane*4];
        float4 v1 = *(const float4*)&hin[(size_t)s1*HH + lane*4];
        acc.x += v0.x + v1.x; acc.y += v0.y + v1.y;
        acc.z += v0.z + v1.z; acc.w += v0.w + v1.w;
    }
    if (j < d){
        int s0 = csr[o + j];
        float4 v0 = *(const float4*)&hin[(size_t)s0*HH + lane*4];
        acc.x += v0.x; acc.y += v0.y; acc.z += v0.z; acc.w += v0.w;
    }
    float id = invd[node];
    float4 r = make_float4(acc.x*id, acc.y*id, acc.z*id, acc.w*id);
    *(float4*)&agg[(size_t)node*HH + lane*4] = r;
}

// ---------------- tiled f32 GEMM: C[M,256] = [A0|A1][M,K] @ Wt[K,256] ----------------
// Wt is pre-transposed to [K][256]. A0 covers k<K0, A1 covers k>=K0 (both row-major, row len = K0 / 256).
template<bool RELU_BIAS>
__global__ __launch_bounds__(256) void k_gemm(
    const float* __restrict__ A0, const float* __restrict__ A1,
    const float* __restrict__ Wt, const float* __restrict__ bias,
    float* __restrict__ C, int M, int K0, int K)
{
    __shared__ float As[64][36];  // [m][k], stride 36 floats = 144B (16B aligned)
    __shared__ float Bs[32][64];  // [k][n]
    const int t  = threadIdx.x;
    const int m0 = blockIdx.y*64, n0 = blockIdx.x*64;
    const int ty = t >> 4, tx = t & 15;       // 16x16 thread grid, 4x4 microtile
    const int ra = t >> 3,  ca = (t & 7)*4;   // A staging: row ra/ra+32, k cols ca..ca+3
    const int rb = t >> 4,  cb = (t & 15)*4;  // B staging: k row rb/rb+16, n cols cb..cb+3

    float acc[4][4] = {};

    for (int k0 = 0; k0 < K; k0 += 32){
        const float* Asrc; int ldA, kb;
        if (k0 < K0){ Asrc = A0; ldA = K0; kb = k0; }
        else        { Asrc = A1; ldA = HH; kb = k0 - K0; }
        #pragma unroll
        for (int p = 0; p < 2; ++p){
            int r = ra + p*32;
            int m = m0 + r;
            float4 av = make_float4(0.f, 0.f, 0.f, 0.f);
            if (m < M) av = *(const float4*)&Asrc[(size_t)m*ldA + kb + ca];
            *(float4*)&As[r][ca] = av;
        }
        #pragma unroll
        for (int p = 0; p < 2; ++p){
            int r = rb + p*16;
            float4 bv = *(const float4*)&Wt[(size_t)(k0 + r)*HH + n0 + cb];
            *(float4*)&Bs[r][cb] = bv;
        }
        __syncthreads();
        #pragma unroll
        for (int kk = 0; kk < 32; ++kk){
            float a[4], b[4];
            #pragma unroll
            for (int i = 0; i < 4; ++i) a[i] = As[ty*4 + i][kk];
            #pragma unroll
            for (int j = 0; j < 4; ++j) b[j] = Bs[kk][tx*4 + j];
            #pragma unroll
            for (int i = 0; i < 4; ++i)
                #pragma unroll
                for (int j = 0; j < 4; ++j)
                    acc[i][j] += a[i]*b[j];
        }
        __syncthreads();
    }

    #pragma unroll
    for (int i = 0; i < 4; ++i){
        int m = m0 + ty*4 + i;
        if (m >= M) continue;
        float4 v = make_float4(acc[i][0], acc[i][1], acc[i][2], acc[i][3]);
        if (RELU_BIAS){
            const float4 bb = *(const float4*)&bias[n0 + tx*4];
            v.x = fmaxf(v.x + bb.x, 0.f); v.y = fmaxf(v.y + bb.y, 0.f);
            v.z = fmaxf(v.z + bb.z, 0.f); v.w = fmaxf(v.w + bb.w, 0.f);
        }
        *(float4*)&C[(size_t)m*HH + n0 + tx*4] = v;
    }
}

// ---------------- LN(+bias) -> ReLU -> +residual, in-place, one wave per row ----------------
__global__ __launch_bounds__(256) void k_ln_relu_res(
    float* __restrict__ hio, const float* __restrict__ res,
    const float* __restrict__ bias, const float* __restrict__ gamma,
    const float* __restrict__ beta)
{
    int wave = threadIdx.x >> 6, lane = threadIdx.x & 63;
    int node = blockIdx.x*4 + wave;
    if (node >= NN) return;
    size_t base = (size_t)node*HH + lane*4;
    float4 v  = *(const float4*)&hio[base];
    float4 bb = *(const float4*)&bias[lane*4];
    v.x += bb.x; v.y += bb.y; v.z += bb.z; v.w += bb.w;
    float s  = v.x + v.y + v.z + v.w;
    float sq = v.x*v.x + v.y*v.y + v.z*v.z + v.w*v.w;
    #pragma unroll
    for (int o = 32; o >= 1; o >>= 1){
        s  += __shfl_xor(s, o);
        sq += __shfl_xor(sq, o);
    }
    float mean = s * (1.0f/HH);
    float var  = sq * (1.0f/HH) - mean*mean;
    float inv  = rsqrtf(var + 1e-5f);
    float4 g  = *(const float4*)&gamma[lane*4];
    float4 be = *(const float4*)&beta[lane*4];
    float4 rr = *(const float4*)&res[base];
    float4 outv;
    outv.x = fmaxf((v.x - mean)*inv*g.x + be.x, 0.f) + rr.x;
    outv.y = fmaxf((v.y - mean)*inv*g.y + be.y, 0.f) + rr.y;
    outv.z = fmaxf((v.z - mean)*inv*g.z + be.z, 0.f) + rr.z;
    outv.w = fmaxf((v.w - mean)*inv*g.w + be.w, 0.f) + rr.w;
    *(float4*)&hio[base] = outv;
}

// ---------------- host ----------------
extern "C" void kernel_launch(void* const* d_in, const int* in_sizes, int n_in,
                              void* d_out, int out_size, void* d_ws, size_t ws_size,
                              hipStream_t stream) {
    const float* x     = (const float*)d_in[0];
    const int*   ei    = (const int*)d_in[1];
    const int*   srcI  = ei;
    const int*   dstI  = ei + EE;
    const float* Wp    = (const float*)d_in[2];
    const float* bp    = (const float*)d_in[3];
    const float* Wl    = (const float*)d_in[4];
    const float* bl    = (const float*)d_in[5];
    const float* Wr    = (const float*)d_in[6];
    const float* gamma = (const float*)d_in[7];
    const float* beta  = (const float*)d_in[8];
    float* out = (float*)d_out;

    char* ws = (char*)d_ws;
    size_t off_b = 0;
    auto alloc = [&](size_t bytes) -> char* {
        char* p = ws + off_b;
        off_b = (off_b + bytes + 255) & ~(size_t)255;
        return p;
    };
    float* A    = (float*)alloc((size_t)NN*HH*4);
    float* B    = (float*)alloc((size_t)NN*HH*4);
    float* AGG  = (float*)alloc((size_t)NN*HH*4);
    int*   csr  = (int*)alloc((size_t)EE*4);
    int*   deg  = (int*)alloc((size_t)NN*4);
    int*   offs = (int*)alloc((size_t)NN*4);
    int*   pos  = (int*)alloc((size_t)NN*4);
    float* invd = (float*)alloc((size_t)NN*4);
    int*   bsum = (int*)alloc(64*4);
    float* Wpt  = (float*)alloc((size_t)FIN*HH*4);
    float* Wt   = (float*)alloc((size_t)NL*2*HH*HH*4);
    (void)ws_size; (void)in_sizes; (void)n_in; (void)out_size;

    const int NB = (NN + 1023)/1024; // 49

    k_zero_i32<<<(NN + 255)/256, 256, 0, stream>>>(deg, NN);
    k_count_deg<<<(EE + 255)/256, 256, 0, stream>>>(dstI, deg);
    k_block_sum<<<NB, 1024, 0, stream>>>(deg, bsum);
    k_scan_bsum<<<1, 1, 0, stream>>>(bsum, NB);
    k_make_off<<<NB, 1024, 0, stream>>>(deg, bsum, offs, pos, invd);
    k_build_csr<<<(EE + 255)/256, 256, 0, stream>>>(srcI, dstI, pos, csr);
    k_transpose_proj<<<(FIN*HH + 255)/256, 256, 0, stream>>>(Wp, Wpt);
    k_transpose_layers<<<(NL*2*HH*HH + 255)/256, 256, 0, stream>>>(Wl, Wr, Wt);

    dim3 ggrid(HH/64, (NN + 63)/64);  // (4, 782)
    k_gemm<true><<<ggrid, 256, 0, stream>>>(x, nullptr, Wpt, bp, A, NN, FIN, FIN);

    float* hin = A;
    for (int l = 0; l < NL; ++l){
        float* hout = (l == NL-1) ? out : ((l == 0) ? B : A);
        k_aggregate<<<(NN + 3)/4, 256, 0, stream>>>(hin, csr, offs, deg, invd, AGG);
        k_gemm<false><<<ggrid, 256, 0, stream>>>(AGG, hin, Wt + (size_t)l*2*HH*HH, nullptr,
                                                 hout, NN, HH, 2*HH);
        k_ln_relu_res<<<(NN + 3)/4, 256, 0, stream>>>(hout, hin, bl + l*HH,
                                                      gamma + l*HH, beta + l*HH);
        hin = hout;
    }
}

// Round 2
// 462.478 us; speedup vs baseline: 2.5863x; 2.5863x over previous
//
#include <hip/hip_runtime.h>

#define NN 50000
#define EE 800000
#define FIN 128
#define HH 256
#define NL 3

#define BM 64
#define BK 32
#define ABYTES (BM*BK*2)          // 4096
#define BBYTES (HH*BK*2)          // 16384
#define TILEB  (ABYTES + BBYTES)  // 20480

typedef __bf16 bf16x8 __attribute__((ext_vector_type(8)));
typedef float  f32x4  __attribute__((ext_vector_type(4)));

__device__ __forceinline__ float bf2f(unsigned short u){
    union { unsigned int i; float f; } v; v.i = ((unsigned int)u) << 16; return v.f;
}
__device__ __forceinline__ unsigned short f2bf(float f){
    union { float f; unsigned int i; } v; v.f = f;
    unsigned int r = v.i + 0x7FFF + ((v.i >> 16) & 1);  // RNE
    return (unsigned short)(r >> 16);
}
__device__ __forceinline__ void gload16(const void* g, void* s){
    __builtin_amdgcn_global_load_lds(
        (const __attribute__((address_space(1))) void*)g,
        (__attribute__((address_space(3))) void*)s, 16, 0, 0);
}

// ---------------- CSR build (unchanged from round 1) ----------------
__global__ void k_zero_i32(int* __restrict__ p, int n){
    int i = blockIdx.x*256 + threadIdx.x;
    if (i < n) p[i] = 0;
}
__global__ void k_count_deg(const int* __restrict__ dst, int* __restrict__ deg){
    int i = blockIdx.x*256 + threadIdx.x;
    if (i < EE) atomicAdd(&deg[dst[i]], 1);
}
__global__ void k_block_sum(const int* __restrict__ deg, int* __restrict__ bsum){
    __shared__ int s[1024];
    int i = blockIdx.x*1024 + threadIdx.x;
    s[threadIdx.x] = (i < NN) ? deg[i] : 0;
    __syncthreads();
    for (int o = 512; o > 0; o >>= 1){
        if (threadIdx.x < o) s[threadIdx.x] += s[threadIdx.x + o];
        __syncthreads();
    }
    if (threadIdx.x == 0) bsum[blockIdx.x] = s[0];
}
__global__ void k_scan_bsum(int* __restrict__ bsum, int nb){
    if (threadIdx.x == 0 && blockIdx.x == 0){
        int run = 0;
        for (int i = 0; i < nb; ++i){ int v = bsum[i]; bsum[i] = run; run += v; }
    }
}
__global__ void k_make_off(const int* __restrict__ deg, const int* __restrict__ bsum,
                           int* __restrict__ off, int* __restrict__ pos,
                           float* __restrict__ invd){
    __shared__ int s[1024];
    int t = threadIdx.x;
    int i = blockIdx.x*1024 + t;
    int v = (i < NN) ? deg[i] : 0;
    s[t] = v; __syncthreads();
    for (int o = 1; o < 1024; o <<= 1){
        int add = (t >= o) ? s[t - o] : 0;
        __syncthreads();
        s[t] += add;
        __syncthreads();
    }
    if (i < NN){
        int excl = s[t] - v + bsum[blockIdx.x];
        off[i] = excl; pos[i] = excl;
        invd[i] = 1.0f / fmaxf((float)v, 1.0f);
    }
}
__global__ void k_build_csr(const int* __restrict__ src, const int* __restrict__ dst,
                            int* __restrict__ pos, int* __restrict__ csr){
    int i = blockIdx.x*256 + threadIdx.x;
    if (i < EE){
        int p = atomicAdd(&pos[dst[i]], 1);
        csr[p] = src[i];
    }
}

// ---------------- casts ----------------
__global__ void k_cast4(const float* __restrict__ in, unsigned short* __restrict__ ob, int n4){
    int i = blockIdx.x*256 + threadIdx.x;
    if (i < n4){
        float4 v = *(const float4*)&in[i*4];
        ushort4 o; o.x=f2bf(v.x); o.y=f2bf(v.y); o.z=f2bf(v.z); o.w=f2bf(v.w);
        *(ushort4*)&ob[i*4] = o;
    }
}
__global__ void k_cast_wcat(const float* __restrict__ Wl, const float* __restrict__ Wr,
                            unsigned short* __restrict__ Wb){
    int i = blockIdx.x*256 + threadIdx.x;   // [l][n][k], k in [0,512)
    if (i < NL*HH*2*HH){
        int k = i & 511; int n = (i >> 9) & 255; int lyr = i >> 17;
        float v = (k < HH) ? Wl[((size_t)(lyr*HH)+n)*HH + k]
                           : Wr[((size_t)(lyr*HH)+n)*HH + (k-HH)];
        Wb[i] = f2bf(v);
    }
}

// ---------------- aggregation: one wave per node, bf16 in/out, f32 accum ----------------
__global__ __launch_bounds__(256) void k_aggregate_bf(
    const unsigned short* __restrict__ hb, const int* __restrict__ csr,
    const int* __restrict__ off, const int* __restrict__ deg,
    const float* __restrict__ invd, unsigned short* __restrict__ aggb)
{
    int wave = threadIdx.x >> 6, lane = threadIdx.x & 63;
    int node = blockIdx.x*4 + wave;
    if (node >= NN) return;
    int o = off[node], d = deg[node];
    float a0=0.f, a1=0.f, a2=0.f, a3=0.f;
    int j = 0;
    for (; j + 2 <= d; j += 2){
        int s0 = csr[o+j], s1 = csr[o+j+1];
        ushort4 v0 = *(const ushort4*)&hb[(size_t)s0*HH + lane*4];
        ushort4 v1 = *(const ushort4*)&hb[(size_t)s1*HH + lane*4];
        a0 += bf2f(v0.x) + bf2f(v1.x); a1 += bf2f(v0.y) + bf2f(v1.y);
        a2 += bf2f(v0.z) + bf2f(v1.z); a3 += bf2f(v0.w) + bf2f(v1.w);
    }
    if (j < d){
        int s0 = csr[o+j];
        ushort4 v0 = *(const ushort4*)&hb[(size_t)s0*HH + lane*4];
        a0 += bf2f(v0.x); a1 += bf2f(v0.y); a2 += bf2f(v0.z); a3 += bf2f(v0.w);
    }
    float id = invd[node];
    ushort4 r; r.x=f2bf(a0*id); r.y=f2bf(a1*id); r.z=f2bf(a2*id); r.w=f2bf(a3*id);
    *(ushort4*)&aggb[(size_t)node*HH + lane*4] = r;
}

// ---------------- MFMA GEMM, BM=64 x BN=256 (full row), fused epilogue ----------------
// C[m, 0:256] = [A0 | A1][m, 0:KTOT] @ Bt^T   (Bt is [256][KTOT] bf16, = B^T)
// EPI 0: out = relu(C + bias)               -> outf (f32) + outb (bf16)
// EPI 1: out = relu(LN(C + bias)) + res     -> outf + outb
// EPI 2: same as 1, f32 only
template<int EPI>
__global__ __launch_bounds__(256) void k_gemm_mfma(
    const unsigned short* __restrict__ A0, int lda0,
    const unsigned short* __restrict__ A1, int lda1,
    const unsigned short* __restrict__ Bt,
    const float* __restrict__ bias,
    const float* __restrict__ gamma, const float* __restrict__ beta,
    const float* __restrict__ res,
    float* __restrict__ outf, unsigned short* __restrict__ outb,
    int K0, int KTOT)
{
    __shared__ char smem[2*TILEB];   // 40 KB: [buf][A 4K | B 16K]
    const int t  = threadIdx.x;
    const int w  = t >> 6, l = t & 63;
    const int lr = l & 15, lg = l >> 4;
    const int m0 = blockIdx.x * BM;

    // ---- staging constants (global src is per-lane; LDS dest is wave-uniform) ----
    // A tile [64 rows][32 bf16]: linear LDS pos p -> row=p>>6, swizzled col; src col = swz^((row&6)<<3)
    const int pA   = w*1024 + l*16;
    const int rowA = pA >> 6;
    const int swzA = (pA & 63) ^ ((rowA & 6) << 3);
    int growA = m0 + rowA; if (growA > NN-1) growA = NN-1;   // clamp; stores masked later
    const char* a0base = (const char*)(A0 + (size_t)growA*lda0) + swzA;
    const char* a1base = (const char*)(A1 + (size_t)growA*lda1) + swzA;
    // B tile [256 rows(n)][32 bf16]
    const char* bbase[4];
    #pragma unroll
    for (int c = 0; c < 4; ++c){
        int p = (w*4 + c)*1024 + l*16;
        int n = p >> 6;
        int swz = (p & 63) ^ ((n & 6) << 3);
        bbase[c] = (const char*)(Bt + (size_t)n*KTOT) + swz;
    }

    f32x4 acc[4][4] = {};   // [m-frag][n-frag]

    auto stage = [&](int s, int buf){
        const int k0 = s * BK;
        char* dst = smem + buf*TILEB;
        const char* gA = (k0 < K0) ? (a0base + (size_t)k0*2)
                                   : (a1base + (size_t)(k0 - K0)*2);
        gload16(gA, dst + w*1024);
        #pragma unroll
        for (int c = 0; c < 4; ++c)
            gload16(bbase[c] + (size_t)k0*2, dst + ABYTES + (w*4 + c)*1024);
    };

    const int nsteps = KTOT / BK;
    stage(0, 0);
    for (int s = 0; s < nsteps; ++s){
        const int cur = s & 1;
        if (s + 1 < nsteps){
            stage(s + 1, cur ^ 1);
            asm volatile("s_waitcnt vmcnt(5)" ::: "memory");  // current tile's 5 loads done
        } else {
            asm volatile("s_waitcnt vmcnt(0)" ::: "memory");
        }
        __builtin_amdgcn_s_barrier();
        __builtin_amdgcn_sched_barrier(0);

        const char* As = smem + cur*TILEB;
        const char* Bs = As + ABYTES;
        const int kb = lg * 16;                  // 16B slot within 64B row
        const int sw = (lr & 6) << 3;            // row-XOR swizzle (row&6 == lr&6 here)
        bf16x8 af[4], bfr[4];
        #pragma unroll
        for (int m = 0; m < 4; ++m){
            int r = m*16 + lr;
            af[m] = *(const bf16x8*)(As + r*64 + (kb ^ sw));
        }
        #pragma unroll
        for (int n = 0; n < 4; ++n){
            int r = w*64 + n*16 + lr;
            bfr[n] = *(const bf16x8*)(Bs + r*64 + (kb ^ sw));
        }
        #pragma unroll
        for (int m = 0; m < 4; ++m)
            #pragma unroll
            for (int n = 0; n < 4; ++n)
                acc[m][n] = __builtin_amdgcn_mfma_f32_16x16x32_bf16(af[m], bfr[n], acc[m][n], 0, 0, 0);

        asm volatile("s_waitcnt lgkmcnt(0)" ::: "memory");
        __builtin_amdgcn_s_barrier();
    }

    // ---- epilogue: C/D layout col=lane&15, row=(lane>>4)*4+reg [m89-verified] ----
    float bcol[4], gcol[4], becol[4];
    #pragma unroll
    for (int n = 0; n < 4; ++n){
        int c = w*64 + n*16 + lr;
        bcol[n] = bias[c];
        if (EPI >= 1){ gcol[n] = gamma[c]; becol[n] = beta[c]; }
    }

    if (EPI == 0){
        #pragma unroll
        for (int m = 0; m < 4; ++m)
        #pragma unroll
        for (int reg = 0; reg < 4; ++reg){
            int R = m*16 + lg*4 + reg;
            int grow = m0 + R;
            if (grow >= NN) continue;
            #pragma unroll
            for (int n = 0; n < 4; ++n){
                int c = w*64 + n*16 + lr;
                float v = fmaxf(acc[m][n][reg] + bcol[n], 0.f);
                outf[(size_t)grow*HH + c] = v;
                outb[(size_t)grow*HH + c] = f2bf(v);
            }
        }
    } else {
        // bias add + per-lane partial row sums over this wave's 64 cols
        float sm[4][4], sq[4][4];
        #pragma unroll
        for (int m = 0; m < 4; ++m)
        #pragma unroll
        for (int reg = 0; reg < 4; ++reg){
            float s = 0.f, q = 0.f;
            #pragma unroll
            for (int n = 0; n < 4; ++n){
                float v = acc[m][n][reg] + bcol[n];
                acc[m][n][reg] = v;
                s += v; q += v*v;
            }
            sm[m][reg] = s; sq[m][reg] = q;
        }
        // reduce across the 16 lanes sharing the same rows (masks 1..8 stay in-group)
        #pragma unroll
        for (int mask = 1; mask <= 8; mask <<= 1){
            #pragma unroll
            for (int m = 0; m < 4; ++m)
            #pragma unroll
            for (int reg = 0; reg < 4; ++reg){
                sm[m][reg] += __shfl_xor(sm[m][reg], mask);
                sq[m][reg] += __shfl_xor(sq[m][reg], mask);
            }
        }
        // cross-wave combine via LDS (tiles dead after last K-step barrier)
        float* red = (float*)smem;   // [wave][64 rows][2]
        __syncthreads();
        if (lr == 0){
            #pragma unroll
            for (int m = 0; m < 4; ++m)
            #pragma unroll
            for (int reg = 0; reg < 4; ++reg){
                int R = m*16 + lg*4 + reg;
                red[(w*64 + R)*2 + 0] = sm[m][reg];
                red[(w*64 + R)*2 + 1] = sq[m][reg];
            }
        }
        __syncthreads();
        #pragma unroll
        for (int m = 0; m < 4; ++m)
        #pragma unroll
        for (int reg = 0; reg < 4; ++reg){
            int R = m*16 + lg*4 + reg;
            float S = 0.f, Q = 0.f;
            #pragma unroll
            for (int ww = 0; ww < 4; ++ww){
                S += red[(ww*64 + R)*2 + 0];
                Q += red[(ww*64 + R)*2 + 1];
            }
            float mean = S * (1.0f/HH);
            float var  = Q * (1.0f/HH) - mean*mean;
            float inv  = rsqrtf(var + 1e-5f);
            int grow = m0 + R;
            if (grow >= NN) continue;
            #pragma unroll
            for (int n = 0; n < 4; ++n){
                int c = w*64 + n*16 + lr;
                float o = fmaxf((acc[m][n][reg] - mean)*inv*gcol[n] + becol[n], 0.f)
                          + res[(size_t)grow*HH + c];
                outf[(size_t)grow*HH + c] = o;
                if (EPI == 1) outb[(size_t)grow*HH + c] = f2bf(o);
            }
        }
    }
}

// ---------------- host ----------------
extern "C" void kernel_launch(void* const* d_in, const int* in_sizes, int n_in,
                              void* d_out, int out_size, void* d_ws, size_t ws_size,
                              hipStream_t stream) {
    const float* x     = (const float*)d_in[0];
    const int*   ei    = (const int*)d_in[1];
    const int*   srcI  = ei;
    const int*   dstI  = ei + EE;
    const float* Wp    = (const float*)d_in[2];
    const float* bp    = (const float*)d_in[3];
    const float* Wl    = (const float*)d_in[4];
    const float* bl    = (const float*)d_in[5];
    const float* Wr    = (const float*)d_in[6];
    const float* gamma = (const float*)d_in[7];
    const float* beta  = (const float*)d_in[8];
    float* out = (float*)d_out;

    char* ws = (char*)d_ws;
    size_t off_b = 0;
    auto alloc = [&](size_t bytes) -> char* {
        char* p = ws + off_b;
        off_b = (off_b + bytes + 255) & ~(size_t)255;
        return p;
    };
    float*          Hf0  = (float*)alloc((size_t)NN*HH*4);
    float*          Hf1  = (float*)alloc((size_t)NN*HH*4);
    unsigned short* Hb   = (unsigned short*)alloc((size_t)NN*HH*2);
    unsigned short* AGGb = (unsigned short*)alloc((size_t)NN*HH*2);
    unsigned short* Xb   = AGGb;  // alias: x_bf16 (12.8 MB) only needed before first aggregate
    int*   csr  = (int*)alloc((size_t)EE*4);
    int*   deg  = (int*)alloc((size_t)NN*4);
    int*   offs = (int*)alloc((size_t)NN*4);
    int*   pos  = (int*)alloc((size_t)NN*4);
    float* invd = (float*)alloc((size_t)NN*4);
    int*   bsum = (int*)alloc(64*4);
    unsigned short* Wpb = (unsigned short*)alloc((size_t)HH*FIN*2);
    unsigned short* Wb  = (unsigned short*)alloc((size_t)NL*HH*2*HH*2);
    (void)ws_size; (void)in_sizes; (void)n_in; (void)out_size;

    const int NB = (NN + 1023)/1024;

    k_zero_i32<<<(NN + 255)/256, 256, 0, stream>>>(deg, NN);
    k_count_deg<<<(EE + 255)/256, 256, 0, stream>>>(dstI, deg);
    k_block_sum<<<NB, 1024, 0, stream>>>(deg, bsum);
    k_scan_bsum<<<1, 1, 0, stream>>>(bsum, NB);
    k_make_off<<<NB, 1024, 0, stream>>>(deg, bsum, offs, pos, invd);
    k_build_csr<<<(EE + 255)/256, 256, 0, stream>>>(srcI, dstI, pos, csr);

    k_cast4<<<(NN*FIN/4 + 255)/256, 256, 0, stream>>>(x, Xb, NN*FIN/4);
    k_cast4<<<(HH*FIN/4 + 255)/256, 256, 0, stream>>>(Wp, Wpb, HH*FIN/4);
    k_cast_wcat<<<(NL*HH*2*HH + 255)/256, 256, 0, stream>>>(Wl, Wr, Wb);

    const int GB = (NN + BM - 1)/BM;  // 782

    // input projection + ReLU -> Hf0 (f32) + Hb (bf16 mirror)
    k_gemm_mfma<0><<<GB, 256, 0, stream>>>(Xb, FIN, Xb, FIN, Wpb, bp,
                                           nullptr, nullptr, nullptr,
                                           Hf0, Hb, FIN, FIN);

    const float* hinf = Hf0;
    for (int lyr = 0; lyr < NL; ++lyr){
        k_aggregate_bf<<<(NN + 3)/4, 256, 0, stream>>>(Hb, csr, offs, deg, invd, AGGb);
        float* houtf = (lyr == NL-1) ? out : ((lyr == 0) ? Hf1 : Hf0);
        const unsigned short* Wbt = Wb + (size_t)lyr*HH*2*HH;
        if (lyr < NL-1)
            k_gemm_mfma<1><<<GB, 256, 0, stream>>>(AGGb, HH, Hb, HH, Wbt, bl + lyr*HH,
                                                   gamma + lyr*HH, beta + lyr*HH, hinf,
                                                   houtf, Hb, HH, 2*HH);
        else
            k_gemm_mfma<2><<<GB, 256, 0, stream>>>(AGGb, HH, Hb, HH, Wbt, bl + lyr*HH,
                                                   gamma + lyr*HH, beta + lyr*HH, hinf,
                                                   houtf, Hb, HH, 2*HH);
        hinf = houtf;
    }
}

// Round 3
// 421.125 us; speedup vs baseline: 2.8403x; 1.0982x over previous
//
#include <hip/hip_runtime.h>

#define NN 50000
#define EE 800000
#define FIN 128
#define HH 256
#define NL 3

#define BM 64
#define BK 32
#define ABYTES (BM*BK*2)          // 4096
#define BBYTES (HH*BK*2)          // 16384
#define TILEB  (ABYTES + BBYTES)  // 20480

typedef __bf16 bf16x8 __attribute__((ext_vector_type(8)));
typedef float  f32x4  __attribute__((ext_vector_type(4)));
typedef unsigned short u16x8 __attribute__((ext_vector_type(8)));

__device__ __forceinline__ float bf2f(unsigned short u){
    union { unsigned int i; float f; } v; v.i = ((unsigned int)u) << 16; return v.f;
}
__device__ __forceinline__ unsigned short f2bf(float f){
    union { float f; unsigned int i; } v; v.f = f;
    unsigned int r = v.i + 0x7FFF + ((v.i >> 16) & 1);  // RNE
    return (unsigned short)(r >> 16);
}
__device__ __forceinline__ void gload16(const void* g, void* s){
    __builtin_amdgcn_global_load_lds(
        (const __attribute__((address_space(1))) void*)g,
        (__attribute__((address_space(3))) void*)s, 16, 0, 0);
}

// ---------------- CSR build ----------------
__global__ void k_zero_i32(int* __restrict__ p, int n){
    int i = blockIdx.x*256 + threadIdx.x;
    if (i < n) p[i] = 0;
}
__global__ void k_count_deg(const int* __restrict__ dst, int* __restrict__ deg){
    int i = blockIdx.x*256 + threadIdx.x;
    if (i < EE) atomicAdd(&deg[dst[i]], 1);
}
__global__ void k_block_sum(const int* __restrict__ deg, int* __restrict__ bsum){
    __shared__ int s[1024];
    int i = blockIdx.x*1024 + threadIdx.x;
    s[threadIdx.x] = (i < NN) ? deg[i] : 0;
    __syncthreads();
    for (int o = 512; o > 0; o >>= 1){
        if (threadIdx.x < o) s[threadIdx.x] += s[threadIdx.x + o];
        __syncthreads();
    }
    if (threadIdx.x == 0) bsum[blockIdx.x] = s[0];
}
__global__ void k_scan_bsum(int* __restrict__ bsum, int nb){
    if (threadIdx.x == 0 && blockIdx.x == 0){
        int run = 0;
        for (int i = 0; i < nb; ++i){ int v = bsum[i]; bsum[i] = run; run += v; }
    }
}
__global__ void k_make_off(const int* __restrict__ deg, const int* __restrict__ bsum,
                           int* __restrict__ off, int* __restrict__ pos,
                           float* __restrict__ invd){
    __shared__ int s[1024];
    int t = threadIdx.x;
    int i = blockIdx.x*1024 + t;
    int v = (i < NN) ? deg[i] : 0;
    s[t] = v; __syncthreads();
    for (int o = 1; o < 1024; o <<= 1){
        int add = (t >= o) ? s[t - o] : 0;
        __syncthreads();
        s[t] += add;
        __syncthreads();
    }
    if (i < NN){
        int excl = s[t] - v + bsum[blockIdx.x];
        off[i] = excl; pos[i] = excl;
        invd[i] = 1.0f / fmaxf((float)v, 1.0f);
    }
}
__global__ void k_build_csr(const int* __restrict__ src, const int* __restrict__ dst,
                            int* __restrict__ pos, int* __restrict__ csr){
    int i = blockIdx.x*256 + threadIdx.x;
    if (i < EE){
        int p = atomicAdd(&pos[dst[i]], 1);
        csr[p] = src[i];
    }
}

// ---------------- casts ----------------
__global__ void k_cast4(const float* __restrict__ in, unsigned short* __restrict__ ob, int n4){
    int i = blockIdx.x*256 + threadIdx.x;
    if (i < n4){
        float4 v = *(const float4*)&in[i*4];
        ushort4 o; o.x=f2bf(v.x); o.y=f2bf(v.y); o.z=f2bf(v.z); o.w=f2bf(v.w);
        *(ushort4*)&ob[i*4] = o;
    }
}
__global__ void k_cast_wcat(const float* __restrict__ Wl, const float* __restrict__ Wr,
                            unsigned short* __restrict__ Wb){
    int i = blockIdx.x*256 + threadIdx.x;   // [l][n][k], k in [0,512)
    if (i < NL*HH*2*HH){
        int k = i & 511; int n = (i >> 9) & 255; int lyr = i >> 17;
        float v = (k < HH) ? Wl[((size_t)(lyr*HH)+n)*HH + k]
                           : Wr[((size_t)(lyr*HH)+n)*HH + (k-HH)];
        Wb[i] = f2bf(v);
    }
}

// ---------------- aggregation v2: wave=node, 16B/lane, 2 rows/instr, 8-deep MLP ----------------
__global__ __launch_bounds__(256) void k_aggregate_bf(
    const unsigned short* __restrict__ hb, const int* __restrict__ csr,
    const int* __restrict__ off, const int* __restrict__ deg,
    const float* __restrict__ invd, unsigned short* __restrict__ aggb)
{
    const int wave = threadIdx.x >> 6, lane = threadIdx.x & 63;
    const int node = blockIdx.x*4 + wave;
    if (node >= NN) return;
    const int o = off[node], d = deg[node];
    const int half = lane >> 5;       // neighbor slot parity
    const int fl   = lane & 31;       // feature group: 8 bf16 = 16B

    float acc[8] = {};
    int j = 0;
    for (; j + 8 <= d; j += 8){
        int s0 = csr[o + j     + half];
        int s1 = csr[o + j + 2 + half];
        int s2 = csr[o + j + 4 + half];
        int s3 = csr[o + j + 6 + half];
        u16x8 v0 = *(const u16x8*)&hb[(size_t)s0*HH + fl*8];
        u16x8 v1 = *(const u16x8*)&hb[(size_t)s1*HH + fl*8];
        u16x8 v2 = *(const u16x8*)&hb[(size_t)s2*HH + fl*8];
        u16x8 v3 = *(const u16x8*)&hb[(size_t)s3*HH + fl*8];
        #pragma unroll
        for (int k = 0; k < 8; ++k)
            acc[k] += (bf2f(v0[k]) + bf2f(v1[k])) + (bf2f(v2[k]) + bf2f(v3[k]));
    }
    for (; j < d; j += 2){
        int idx = j + half;
        if (idx < d){
            int s = csr[o + idx];
            u16x8 v = *(const u16x8*)&hb[(size_t)s*HH + fl*8];
            #pragma unroll
            for (int k = 0; k < 8; ++k) acc[k] += bf2f(v[k]);
        }
    }
    #pragma unroll
    for (int k = 0; k < 8; ++k) acc[k] += __shfl_xor(acc[k], 32);

    if (half == 0){
        float id = invd[node];
        u16x8 r;
        #pragma unroll
        for (int k = 0; k < 8; ++k) r[k] = f2bf(acc[k]*id);
        *(u16x8*)&aggb[(size_t)node*HH + fl*8] = r;
    }
}

// ---------------- MFMA GEMM, BM=64 x BN=256 (full row), fused epilogue ----------------
// C[m, 0:256] = [A0 | A1][m, 0:KTOT] @ Bt^T   (Bt is [256][KTOT] bf16, = B^T)
// EPI 0: outb = bf16(relu(C + bias))
// EPI 1: outb = bf16(relu(LN(C + bias)) + resb)
// EPI 2: outf = relu(LN(C + bias)) + resb      (final layer, f32)
template<int EPI>
__global__ __launch_bounds__(256) void k_gemm_mfma(
    const unsigned short* __restrict__ A0, int lda0,
    const unsigned short* __restrict__ A1, int lda1,
    const unsigned short* __restrict__ Bt,
    const float* __restrict__ bias,
    const float* __restrict__ gamma, const float* __restrict__ beta,
    const unsigned short* __restrict__ resb,
    float* __restrict__ outf, unsigned short* __restrict__ outb,
    int K0, int KTOT)
{
    __shared__ char smem[2*TILEB];   // 40 KB: [buf][A 4K | B 16K]
    const int t  = threadIdx.x;
    const int w  = t >> 6, l = t & 63;
    const int lr = l & 15, lg = l >> 4;
    const int m0 = blockIdx.x * BM;

    // ---- staging (global src per-lane pre-swizzled; LDS dest linear: rule #21) ----
    const int pA   = w*1024 + l*16;
    const int rowA = pA >> 6;
    const int swzA = (pA & 63) ^ ((rowA & 6) << 3);
    int growA = m0 + rowA; if (growA > NN-1) growA = NN-1;   // clamp; stores masked later
    const char* a0base = (const char*)(A0 + (size_t)growA*lda0) + swzA;
    const char* a1base = (const char*)(A1 + (size_t)growA*lda1) + swzA;
    const char* bbase[4];
    #pragma unroll
    for (int c = 0; c < 4; ++c){
        int p = (w*4 + c)*1024 + l*16;
        int n = p >> 6;
        int swz = (p & 63) ^ ((n & 6) << 3);
        bbase[c] = (const char*)(Bt + (size_t)n*KTOT) + swz;
    }

    f32x4 acc[4][4] = {};   // [m-frag][n-frag]

    auto stage = [&](int s, int buf){
        const int k0 = s * BK;
        char* dst = smem + buf*TILEB;
        const char* gA = (k0 < K0) ? (a0base + (size_t)k0*2)
                                   : (a1base + (size_t)(k0 - K0)*2);
        gload16(gA, dst + w*1024);
        #pragma unroll
        for (int c = 0; c < 4; ++c)
            gload16(bbase[c] + (size_t)k0*2, dst + ABYTES + (w*4 + c)*1024);
    };

    const int nsteps = KTOT / BK;
    stage(0, 0);
    for (int s = 0; s < nsteps; ++s){
        const int cur = s & 1;
        if (s + 1 < nsteps){
            stage(s + 1, cur ^ 1);
            asm volatile("s_waitcnt vmcnt(5)" ::: "memory");
        } else {
            asm volatile("s_waitcnt vmcnt(0)" ::: "memory");
        }
        __builtin_amdgcn_s_barrier();
        __builtin_amdgcn_sched_barrier(0);

        const char* As = smem + cur*TILEB;
        const char* Bs = As + ABYTES;
        const int kb = lg * 16;
        const int sw = (lr & 6) << 3;
        bf16x8 af[4], bfr[4];
        #pragma unroll
        for (int m = 0; m < 4; ++m){
            int r = m*16 + lr;
            af[m] = *(const bf16x8*)(As + r*64 + (kb ^ sw));
        }
        #pragma unroll
        for (int n = 0; n < 4; ++n){
            int r = w*64 + n*16 + lr;
            bfr[n] = *(const bf16x8*)(Bs + r*64 + (kb ^ sw));
        }
        #pragma unroll
        for (int m = 0; m < 4; ++m)
            #pragma unroll
            for (int n = 0; n < 4; ++n)
                acc[m][n] = __builtin_amdgcn_mfma_f32_16x16x32_bf16(af[m], bfr[n], acc[m][n], 0, 0, 0);

        asm volatile("s_waitcnt lgkmcnt(0)" ::: "memory");
        __builtin_amdgcn_s_barrier();
    }

    // ---- epilogue: C/D layout col=lane&15, row=(lane>>4)*4+reg [m89-verified] ----
    float bcol[4], gcol[4], becol[4];
    #pragma unroll
    for (int n = 0; n < 4; ++n){
        int c = w*64 + n*16 + lr;
        bcol[n] = bias[c];
        if (EPI >= 1){ gcol[n] = gamma[c]; becol[n] = beta[c]; }
    }

    if (EPI == 0){
        #pragma unroll
        for (int m = 0; m < 4; ++m)
        #pragma unroll
        for (int reg = 0; reg < 4; ++reg){
            int R = m*16 + lg*4 + reg;
            int grow = m0 + R;
            if (grow >= NN) continue;
            #pragma unroll
            for (int n = 0; n < 4; ++n){
                int c = w*64 + n*16 + lr;
                float v = fmaxf(acc[m][n][reg] + bcol[n], 0.f);
                outb[(size_t)grow*HH + c] = f2bf(v);
            }
        }
    } else {
        float sm[4][4], sq[4][4];
        #pragma unroll
        for (int m = 0; m < 4; ++m)
        #pragma unroll
        for (int reg = 0; reg < 4; ++reg){
            float s = 0.f, q = 0.f;
            #pragma unroll
            for (int n = 0; n < 4; ++n){
                float v = acc[m][n][reg] + bcol[n];
                acc[m][n][reg] = v;
                s += v; q += v*v;
            }
            sm[m][reg] = s; sq[m][reg] = q;
        }
        #pragma unroll
        for (int mask = 1; mask <= 8; mask <<= 1){
            #pragma unroll
            for (int m = 0; m < 4; ++m)
            #pragma unroll
            for (int reg = 0; reg < 4; ++reg){
                sm[m][reg] += __shfl_xor(sm[m][reg], mask);
                sq[m][reg] += __shfl_xor(sq[m][reg], mask);
            }
        }
        float* red = (float*)smem;   // [wave][64 rows][2]; tiles dead after last barrier
        __syncthreads();
        if (lr == 0){
            #pragma unroll
            for (int m = 0; m < 4; ++m)
            #pragma unroll
            for (int reg = 0; reg < 4; ++reg){
                int R = m*16 + lg*4 + reg;
                red[(w*64 + R)*2 + 0] = sm[m][reg];
                red[(w*64 + R)*2 + 1] = sq[m][reg];
            }
        }
        __syncthreads();
        #pragma unroll
        for (int m = 0; m < 4; ++m)
        #pragma unroll
        for (int reg = 0; reg < 4; ++reg){
            int R = m*16 + lg*4 + reg;
            float S = 0.f, Q = 0.f;
            #pragma unroll
            for (int ww = 0; ww < 4; ++ww){
                S += red[(ww*64 + R)*2 + 0];
                Q += red[(ww*64 + R)*2 + 1];
            }
            float mean = S * (1.0f/HH);
            float var  = Q * (1.0f/HH) - mean*mean;
            float inv  = rsqrtf(var + 1e-5f);
            int grow = m0 + R;
            if (grow >= NN) continue;
            #pragma unroll
            for (int n = 0; n < 4; ++n){
                int c = w*64 + n*16 + lr;
                float o = fmaxf((acc[m][n][reg] - mean)*inv*gcol[n] + becol[n], 0.f)
                          + bf2f(resb[(size_t)grow*HH + c]);
                if (EPI == 1) outb[(size_t)grow*HH + c] = f2bf(o);
                else          outf[(size_t)grow*HH + c] = o;
            }
        }
    }
}

// ---------------- host ----------------
extern "C" void kernel_launch(void* const* d_in, const int* in_sizes, int n_in,
                              void* d_out, int out_size, void* d_ws, size_t ws_size,
                              hipStream_t stream) {
    const float* x     = (const float*)d_in[0];
    const int*   ei    = (const int*)d_in[1];
    const int*   srcI  = ei;
    const int*   dstI  = ei + EE;
    const float* Wp    = (const float*)d_in[2];
    const float* bp    = (const float*)d_in[3];
    const float* Wl    = (const float*)d_in[4];
    const float* bl    = (const float*)d_in[5];
    const float* Wr    = (const float*)d_in[6];
    const float* gamma = (const float*)d_in[7];
    const float* beta  = (const float*)d_in[8];
    float* out = (float*)d_out;

    char* ws = (char*)d_ws;
    size_t off_b = 0;
    auto alloc = [&](size_t bytes) -> char* {
        char* p = ws + off_b;
        off_b = (off_b + bytes + 255) & ~(size_t)255;
        return p;
    };
    unsigned short* Hb0  = (unsigned short*)alloc((size_t)NN*HH*2);
    unsigned short* Hb1  = (unsigned short*)alloc((size_t)NN*HH*2);
    unsigned short* AGGb = (unsigned short*)alloc((size_t)NN*HH*2);
    unsigned short* Xb   = AGGb;  // alias: x_bf16 only needed before first aggregate
    int*   csr  = (int*)alloc((size_t)EE*4);
    int*   deg  = (int*)alloc((size_t)NN*4);
    int*   offs = (int*)alloc((size_t)NN*4);
    int*   pos  = (int*)alloc((size_t)NN*4);
    float* invd = (float*)alloc((size_t)NN*4);
    int*   bsum = (int*)alloc(64*4);
    unsigned short* Wpb = (unsigned short*)alloc((size_t)HH*FIN*2);
    unsigned short* Wb  = (unsigned short*)alloc((size_t)NL*HH*2*HH*2);
    (void)ws_size; (void)in_sizes; (void)n_in; (void)out_size;

    const int NB = (NN + 1023)/1024;

    k_zero_i32<<<(NN + 255)/256, 256, 0, stream>>>(deg, NN);
    k_count_deg<<<(EE + 255)/256, 256, 0, stream>>>(dstI, deg);
    k_block_sum<<<NB, 1024, 0, stream>>>(deg, bsum);
    k_scan_bsum<<<1, 1, 0, stream>>>(bsum, NB);
    k_make_off<<<NB, 1024, 0, stream>>>(deg, bsum, offs, pos, invd);
    k_build_csr<<<(EE + 255)/256, 256, 0, stream>>>(srcI, dstI, pos, csr);

    k_cast4<<<(NN*FIN/4 + 255)/256, 256, 0, stream>>>(x, Xb, NN*FIN/4);
    k_cast4<<<(HH*FIN/4 + 255)/256, 256, 0, stream>>>(Wp, Wpb, HH*FIN/4);
    k_cast_wcat<<<(NL*HH*2*HH + 255)/256, 256, 0, stream>>>(Wl, Wr, Wb);

    const int GB = (NN + BM - 1)/BM;  // 782

    // input projection + ReLU -> Hb0 (bf16)
    k_gemm_mfma<0><<<GB, 256, 0, stream>>>(Xb, FIN, Xb, FIN, Wpb, bp,
                                           nullptr, nullptr, nullptr,
                                           nullptr, Hb0, FIN, FIN);

    unsigned short* hin = Hb0;
    for (int lyr = 0; lyr < NL; ++lyr){
        k_aggregate_bf<<<(NN + 3)/4, 256, 0, stream>>>(hin, csr, offs, deg, invd, AGGb);
        unsigned short* hout = (hin == Hb0) ? Hb1 : Hb0;
        const unsigned short* Wbt = Wb + (size_t)lyr*HH*2*HH;
        if (lyr < NL-1)
            k_gemm_mfma<1><<<GB, 256, 0, stream>>>(AGGb, HH, hin, HH, Wbt, bl + lyr*HH,
                                                   gamma + lyr*HH, beta + lyr*HH, hin,
                                                   nullptr, hout, HH, 2*HH);
        else
            k_gemm_mfma<2><<<GB, 256, 0, stream>>>(AGGb, HH, hin, HH, Wbt, bl + lyr*HH,
                                                   gamma + lyr*HH, beta + lyr*HH, hin,
                                                   out, nullptr, HH, 2*HH);
        hin = hout;
    }
}